// Round 2
// 488.495 us; speedup vs baseline: 1.0111x; 1.0111x over previous
//
#include <hip/hip_runtime.h>

// ManifoldNetSPD SPD identity-pad:
//   x: [8,16,256,256,3,3] f32  ->  out: [8,16,258,258,3,3] f32
//   border cells (i or j on the 1-wide pad ring) = eye(3), interior = copy.
//
// Single-phase design: one block per OUTPUT row (grid = 258 rows x 128 images).
//  - interior rows (i in [1,257)): copy 2304 floats (576 float4) from src row i-1,
//    plus the row's own 18 border floats (left/right eye cells).
//  - border rows (i==0 / i==257): write the repeating eye pattern, vectorized.
// This removes the previous kernel's trailing border phase (2048 blocks of
// 64-bit div/mod + scattered 36B writes that ran as a serial tail after the
// copy blocks drained) and gives every output row a single contiguous writer.
//
// Mandatory traffic: 302 MB read + 307 MB write = 609 MB -> ~97 us at 6.3 TB/s.
// (Round 1: resubmission of Round 0 kernel — bench failed on container
//  acquisition, not on the kernel; no correctness/timing signal was produced.)

constexpr int B  = 8;
constexpr int C  = 16;
constexpr int H  = 256;
constexpr int W  = 256;
constexpr int HP = 258;   // H + 2
constexpr int WP = 258;   // W + 2

constexpr int       IMGS    = B * C;                        // 128
constexpr long long ROW_IN  = (long long)W * 9;             // 2304 floats
constexpr long long IMG_IN  = (long long)H * ROW_IN;
constexpr long long ROW_OUT = (long long)WP * 9;            // 2322 floats
constexpr long long IMG_OUT = (long long)HP * ROW_OUT;      // 599076 floats

// Row layout (floats): [0..8] left eye cell | [9..2312] interior (2304) | [2313..2321] right eye cell
constexpr int F4_PER_ROW_OUT = 580;   // 580*4 = 2320, +2 scalar tail
constexpr int F4_PER_COPY    = 576;   // 2304/4 = 192 threads * 3

__global__ __launch_bounds__(192) void spd_pad_kernel(const float* __restrict__ x,
                                                      float* __restrict__ out) {
    const int i   = blockIdx.x;   // output row 0..257
    const int img = blockIdx.y;   // 0..127
    const int tid = threadIdx.x;  // 0..191 (3 waves)

    float* __restrict__ rowp = out + (long long)img * IMG_OUT + (long long)i * ROW_OUT;

    if (i != 0 && i != HP - 1) {
        // ---- interior row: contiguous 576-float4 copy + own border cells ----
        const float4* __restrict__ src4 =
            reinterpret_cast<const float4*>(x + (long long)img * IMG_IN + (long long)(i - 1) * ROW_IN);
        float4* __restrict__ dst4 = reinterpret_cast<float4*>(rowp + 9);
#pragma unroll
        for (int k = 0; k < 3; ++k) {
            const int idx = tid + k * 192;   // 0..575, every thread exactly 3
            dst4[idx] = src4[idx];
        }
        if (tid < 18) {
            const int   e = (tid < 9) ? tid : tid - 9;
            const float v = (e == 0 || e == 4 || e == 8) ? 1.0f : 0.0f;
            rowp[(tid < 9) ? e : (2313 + e)] = v;
        }
    } else {
        // ---- pure border row (only 2 per image): repeating eye(3) pattern ----
        float4* __restrict__ dst4 = reinterpret_cast<float4*>(rowp);
        for (int f4 = tid; f4 < F4_PER_ROW_OUT; f4 += 192) {
            int m = (f4 * 4) % 9;   // element index within 3x3 cell
            float4 v;
            v.x = (m == 0 || m == 4 || m == 8) ? 1.0f : 0.0f; m = (m == 8) ? 0 : m + 1;
            v.y = (m == 0 || m == 4 || m == 8) ? 1.0f : 0.0f; m = (m == 8) ? 0 : m + 1;
            v.z = (m == 0 || m == 4 || m == 8) ? 1.0f : 0.0f; m = (m == 8) ? 0 : m + 1;
            v.w = (m == 0 || m == 4 || m == 8) ? 1.0f : 0.0f;
            dst4[f4] = v;
        }
        if (tid < 2) {
            // tail floats 2320 (e=7 -> 0) and 2321 (e=8 -> 1)
            rowp[2320 + tid] = (tid == 1) ? 1.0f : 0.0f;
        }
    }
}

extern "C" void kernel_launch(void* const* d_in, const int* in_sizes, int n_in,
                              void* d_out, int out_size, void* d_ws, size_t ws_size,
                              hipStream_t stream) {
    const float* x   = (const float*)d_in[0];
    float*       out = (float*)d_out;
    // d_in[1] is padding_dim (==1), baked into the constants above.
    spd_pad_kernel<<<dim3(HP, IMGS), dim3(192), 0, stream>>>(x, out);
}